// Round 3
// baseline (161.875 us; speedup 1.0000x reference)
//
#include <hip/hip_runtime.h>
#include <math.h>

// x: [64, 256, 32, 32] fp32. One block per channel; channel data (64K floats)
// lives in registers (16 float4/thread x 1024 threads).
#define C_DIM    256
#define M_DIM    65536
#define K_TOP    100
#define EPS_F    1e-7f
#define THREADS  1024
#define NWAVES   (THREADS / 64)
#define CAP      8192
#define F4_STRIDE 262144   // 4 slabs * 16384 float4/channel-slab-group (i stride)

#define FOR4(Q, V, BODY) \
    { { const float V = (Q).x; BODY } { const float V = (Q).y; BODY } \
      { const float V = (Q).z; BODY } { const float V = (Q).w; BODY } }

__device__ __forceinline__ unsigned int wave_suffix_u32(unsigned int v, int lane)
{
    #pragma unroll
    for (int off = 1; off < 64; off <<= 1) {
        unsigned int o = __shfl_down(v, off, 64);
        if (lane + off < 64) v += o;
    }
    return v;   // suffix-inclusive sum over lanes >= lane
}

__device__ __forceinline__ double block_sum_double(double v, double* dred, int tid)
{
    const int lane = tid & 63, wv = tid >> 6;
    #pragma unroll
    for (int off = 1; off < 64; off <<= 1) {
        double o = __shfl_down(v, off, 64);
        if (lane + off < 64) v += o;
    }
    __syncthreads();                 // protect dred reuse
    if (lane == 0) dred[wv] = v;     // lane0 holds wave total
    __syncthreads();
    double r = 0.0;
    if (tid == 0) {
        #pragma unroll
        for (int i = 0; i < NWAVES; ++i) r += dred[i];
    }
    return r;   // valid on tid 0 only
}

// Find, in hist[0..nbins) (bins ascending in value), the bin holding the
// Krem-th largest element. Writes bin and count-strictly-above to LDS outs.
// 2 barriers + 1 trailing (vs 20 for Hillis-Steele over 1024).
__device__ __forceinline__ void select_bin(
    const unsigned int* hist, int nbins, unsigned int Krem,
    unsigned int* wtot, unsigned int* wsuf,
    unsigned int* out_bin, unsigned int* out_cnt, int tid)
{
    const int lane = tid & 63, wv = tid >> 6;
    const int bpt = (nbins + THREADS - 1) / THREADS;
    const int lo = tid * bpt;
    const int hi = min(nbins, lo + bpt);
    unsigned int s = 0;
    for (int b = lo; b < hi; ++b) s += hist[b];
    const unsigned int ws = wave_suffix_u32(s, lane);
    if (lane == 0) wtot[wv] = ws;
    __syncthreads();
    if (tid < NWAVES) {
        unsigned int t = 0;
        for (int j = tid; j < NWAVES; ++j) t += wtot[j];
        wsuf[tid] = t;
    }
    __syncthreads();
    const unsigned int above_w = (wv + 1 < NWAVES) ? wsuf[wv + 1] : 0u;
    const unsigned int incl   = ws + above_w;    // count in bins >= lo
    const unsigned int S_excl = incl - s;        // count in bins > my range
    if (S_excl < Krem && incl >= Krem) {         // exactly one thread
        unsigned int cum = S_excl;
        for (int b = hi - 1; b >= lo; --b) {
            unsigned int h = hist[b];
            if (cum + h >= Krem) { *out_bin = (unsigned int)b; *out_cnt = cum; break; }
            cum += h;
        }
    }
    __syncthreads();
}

__global__ __launch_bounds__(THREADS) void fused_kernel(
    const float4* __restrict__ x4, const float* __restrict__ weight,
    const float* __restrict__ bias, float4* __restrict__ out4, float cconst)
{
    const int c = blockIdx.x;
    const int tid = threadIdx.x;

    __shared__ unsigned int hist[4096];
    __shared__ unsigned int cand[CAP];
    __shared__ unsigned int wtot[NWAVES], wsuf[NWAVES];
    __shared__ double dred[NWAVES];
    __shared__ float s_mean, s_alpha, s_beta;
    __shared__ unsigned int s_bin, s_cnt, s_ccnt;

    // ---- the ONLY global read: channel slice into registers ----
    // idx(g) = ((g>>8)*256 + c)*256 + (g&255); g = tid + i*1024
    const size_t base = ((size_t)(tid >> 8) << 16) + ((size_t)c << 8) + (size_t)(tid & 255);
    const float4* xp = x4 + base;
    float4 vals[16];
    #pragma unroll
    for (int i = 0; i < 16; ++i) vals[i] = xp[(size_t)i * F4_STRIDE];

    // ---- mean (double accumulate) ----
    double s = 0.0;
    #pragma unroll
    for (int i = 0; i < 16; ++i)
        s += ((double)vals[i].x + (double)vals[i].y) + ((double)vals[i].z + (double)vals[i].w);
    double tot = block_sum_double(s, dred, tid);
    if (tid == 0) s_mean = (float)(tot / (double)M_DIM);

    // ---- 12-bit histogram of |x - mean| from registers ----
    #pragma unroll
    for (int i = 0; i < 4; ++i) hist[tid + (i << 10)] = 0u;
    __syncthreads();                    // also publishes s_mean
    const float mean = s_mean;
    #pragma unroll
    for (int i = 0; i < 16; ++i) {
        float4 q = vals[i];
        FOR4(q, v, {
            unsigned int u = __float_as_uint(fabsf(v - mean));
            atomicAdd(&hist[u >> 20], 1u);
        })
    }
    __syncthreads();

    select_bin(hist, 4096, K_TOP, wtot, wsuf, &s_bin, &s_cnt, tid);
    const unsigned int b1 = s_bin;
    const unsigned int n1 = s_cnt;          // strictly above bin b1
    const unsigned int inb1 = hist[b1];
    const unsigned int K2 = K_TOP - n1;

    unsigned int vk_bits;
    unsigned int cnt_gt = n1;
    double sum_gt;

    if (n1 + inb1 <= CAP) {
        // ---- fast path: collect candidate bits (top-12 >= b1) into LDS ----
        if (tid == 0) s_ccnt = 0u;
        __syncthreads();
        #pragma unroll
        for (int i = 0; i < 16; ++i) {
            float4 q = vals[i];
            FOR4(q, v, {
                unsigned int u = __float_as_uint(fabsf(v - mean));
                if ((u >> 20) >= b1) {
                    unsigned int p = atomicAdd(&s_ccnt, 1u);
                    if (p < CAP) cand[p] = u;
                }
            })
        }
        __syncthreads();
        const unsigned int cnt = s_ccnt;

        // level 2: bits [19:8] among top-12 == b1
        #pragma unroll
        for (int i = 0; i < 4; ++i) hist[tid + (i << 10)] = 0u;
        __syncthreads();
        for (unsigned int i = tid; i < cnt; i += THREADS) {
            unsigned int u = cand[i];
            if ((u >> 20) == b1) atomicAdd(&hist[(u >> 8) & 0xFFFu], 1u);
        }
        __syncthreads();
        select_bin(hist, 4096, K2, wtot, wsuf, &s_bin, &s_cnt, tid);
        const unsigned int b2 = s_bin;
        const unsigned int K3 = K2 - s_cnt;
        const unsigned int pfx24 = (b1 << 12) | b2;
        cnt_gt += s_cnt;

        // level 3: bits [7:0] among top-24 == pfx24
        if (tid < 256) hist[tid] = 0u;
        __syncthreads();
        for (unsigned int i = tid; i < cnt; i += THREADS) {
            unsigned int u = cand[i];
            if ((u >> 8) == pfx24) atomicAdd(&hist[u & 0xFFu], 1u);
        }
        __syncthreads();
        select_bin(hist, 256, K3, wtot, wsuf, &s_bin, &s_cnt, tid);
        cnt_gt += s_cnt;
        vk_bits = (pfx24 << 8) | s_bin;

        // sum of candidates strictly above v_K
        double sg = 0.0;
        for (unsigned int i = tid; i < cnt; i += THREADS) {
            unsigned int u = cand[i];
            if (u > vk_bits) sg += (double)__uint_as_float(u);
        }
        sum_gt = block_sum_double(sg, dred, tid);
    } else {
        // ---- exact fallback from registers (degenerate distributions) ----
        #pragma unroll
        for (int i = 0; i < 4; ++i) hist[tid + (i << 10)] = 0u;
        __syncthreads();
        #pragma unroll
        for (int i = 0; i < 16; ++i) {
            float4 q = vals[i];
            FOR4(q, v, {
                unsigned int u = __float_as_uint(fabsf(v - mean));
                if ((u >> 20) == b1) atomicAdd(&hist[(u >> 8) & 0xFFFu], 1u);
            })
        }
        __syncthreads();
        select_bin(hist, 4096, K2, wtot, wsuf, &s_bin, &s_cnt, tid);
        const unsigned int b2 = s_bin;
        const unsigned int K3 = K2 - s_cnt;
        const unsigned int pfx24 = (b1 << 12) | b2;
        cnt_gt += s_cnt;

        if (tid < 256) hist[tid] = 0u;
        __syncthreads();
        #pragma unroll
        for (int i = 0; i < 16; ++i) {
            float4 q = vals[i];
            FOR4(q, v, {
                unsigned int u = __float_as_uint(fabsf(v - mean));
                if ((u >> 8) == pfx24) atomicAdd(&hist[u & 0xFFu], 1u);
            })
        }
        __syncthreads();
        select_bin(hist, 256, K3, wtot, wsuf, &s_bin, &s_cnt, tid);
        cnt_gt += s_cnt;
        vk_bits = (pfx24 << 8) | s_bin;

        double sg = 0.0;
        #pragma unroll
        for (int i = 0; i < 16; ++i) {
            float4 q = vals[i];
            FOR4(q, v, {
                float a = fabsf(v - mean);
                if (__float_as_uint(a) > vk_bits) sg += (double)a;
            })
        }
        sum_gt = block_sum_double(sg, dred, tid);
    }

    // ---- alpha/beta ----
    if (tid == 0) {
        const float vK = __uint_as_float(vk_bits);
        const double top_sum = sum_gt + (double)(K_TOP - cnt_gt) * (double)vK;
        const float mean_topk = (float)(top_sum / (double)K_TOP) * cconst;
        const float scale = 1.0f / (mean_topk + EPS_F);
        const float a = scale * weight[c];
        s_alpha = a;
        s_beta  = bias[c] - mean * a;
    }
    __syncthreads();

    // ---- the ONLY global write: apply from registers ----
    const float a = s_alpha, b = s_beta;
    float4* op = out4 + base;
    #pragma unroll
    for (int i = 0; i < 16; ++i) {
        float4 v = vals[i], o;
        o.x = fmaf(v.x, a, b);
        o.y = fmaf(v.y, a, b);
        o.z = fmaf(v.z, a, b);
        o.w = fmaf(v.w, a, b);
        op[(size_t)i * F4_STRIDE] = o;
    }
}

// ---------------------------------------------------------------------------
extern "C" void kernel_launch(void* const* d_in, const int* in_sizes, int n_in,
                              void* d_out, int out_size, void* d_ws, size_t ws_size,
                              hipStream_t stream)
{
    const float* x = (const float*)d_in[0];
    const float* w = (const float*)d_in[1];
    const float* b = (const float*)d_in[2];
    float* out = (float*)d_out;

    const int M = in_sizes[0] / in_sizes[1];   // 65536
    const double cst = 0.5 * (1.0 + sqrt(M_PI * log(4.0))) / sqrt(2.0 * log((double)M));

    fused_kernel<<<C_DIM, THREADS, 0, stream>>>(
        (const float4*)x, w, b, (float4*)out, (float)cst);
}

// Round 5
// 138.512 us; speedup vs baseline: 1.1687x; 1.1687x over previous
//
#include <hip/hip_runtime.h>
#include <math.h>

// x: [64, 256, 32, 32] fp32. One block (1024 thr) per channel.
// Pass 1: stream channel -> mean sum + collect candidates |x| >= T into LDS
//         (wave-aggregated ballot push, 1 LDS atomic per wave per quad-lane).
// Select v_K + topK-sum among candidates in LDS (validity proven exactly;
// fallback = exact global radix select). Pass 2: apply out = x*alpha + beta.
#define C_DIM    256
#define M_DIM    65536
#define K_TOP    100
#define EPS_F    1e-7f
#define THREADS  1024
#define NWAVES   (THREADS / 64)
#define CAP      8192
#define F4_STRIDE 262144        // element-i stride between a thread's float4 loads
#define T_FAST   2.0f           // candidate threshold (validity checked exactly)

typedef float f4v __attribute__((ext_vector_type(4)));

#define FOR4(Q, V, BODY) \
    { { const float V = (Q).x; BODY } { const float V = (Q).y; BODY } \
      { const float V = (Q).z; BODY } { const float V = (Q).w; BODY } }

// Wave-aggregated LDS append: pred lanes write bits to buf in lane order.
// All 64 lanes must reach this call (pred may diverge).
__device__ __forceinline__ void wave_append(
    bool pred, unsigned int bits, unsigned int* buf, unsigned int cap,
    unsigned int* counter, int lane)
{
    unsigned long long mask = __ballot(pred);
    if (mask == 0ull) return;                     // wave-uniform
    const int leader = __ffsll((unsigned long long)mask) - 1;
    unsigned int wbase = 0u;
    if (lane == leader) wbase = atomicAdd(counter, (unsigned int)__popcll(mask));
    wbase = __shfl(wbase, leader, 64);
    if (pred) {
        unsigned int p = wbase + (unsigned int)__popcll(mask & ((1ull << lane) - 1ull));
        if (p < cap) buf[p] = bits;
    }
}

__device__ __forceinline__ unsigned int wave_suffix_u32(unsigned int v, int lane)
{
    #pragma unroll
    for (int off = 1; off < 64; off <<= 1) {
        unsigned int o = __shfl_down(v, off, 64);
        if (lane + off < 64) v += o;
    }
    return v;   // suffix-inclusive sum over lanes >= lane
}

__device__ __forceinline__ double block_sum_double(double v, double* dred, int tid)
{
    const int lane = tid & 63, wv = tid >> 6;
    #pragma unroll
    for (int off = 1; off < 64; off <<= 1) {
        double o = __shfl_down(v, off, 64);
        if (lane + off < 64) v += o;
    }
    __syncthreads();                 // protect dred reuse
    if (lane == 0) dred[wv] = v;
    __syncthreads();
    double r = 0.0;
    if (tid == 0) {
        #pragma unroll
        for (int i = 0; i < NWAVES; ++i) r += dred[i];
    }
    return r;   // valid on tid 0 only
}

// Find, in hist[0..nbins) (bins ascending in value), the bin holding the
// Krem-th largest element. Writes bin + count-strictly-above to LDS outs.
__device__ __forceinline__ void select_bin(
    const unsigned int* hist, int nbins, unsigned int Krem,
    unsigned int* wtot, unsigned int* wsuf,
    unsigned int* out_bin, unsigned int* out_cnt, int tid)
{
    const int lane = tid & 63, wv = tid >> 6;
    const int bpt = (nbins + THREADS - 1) / THREADS;
    const int lo = tid * bpt;
    const int hi = min(nbins, lo + bpt);
    unsigned int s = 0;
    for (int b = lo; b < hi; ++b) s += hist[b];
    const unsigned int ws = wave_suffix_u32(s, lane);
    if (lane == 0) wtot[wv] = ws;
    __syncthreads();
    if (tid < NWAVES) {
        unsigned int t = 0;
        for (int j = tid; j < NWAVES; ++j) t += wtot[j];
        wsuf[tid] = t;
    }
    __syncthreads();
    const unsigned int above_w = (wv + 1 < NWAVES) ? wsuf[wv + 1] : 0u;
    const unsigned int incl   = ws + above_w;    // count in bins >= lo
    const unsigned int S_excl = incl - s;        // count in bins > my range
    if (S_excl < Krem && incl >= Krem) {         // exactly one thread
        unsigned int cum = S_excl;
        for (int b = hi - 1; b >= lo; --b) {
            unsigned int h = hist[b];
            if (cum + h >= Krem) { *out_bin = (unsigned int)b; *out_cnt = cum; break; }
            cum += h;
        }
    }
    __syncthreads();
}

__global__ __launch_bounds__(THREADS) void fused_kernel(
    const float4* __restrict__ x4, const float* __restrict__ weight,
    const float* __restrict__ bias, float4* __restrict__ out4, float cconst)
{
    const int c = blockIdx.x;
    const int tid = threadIdx.x;
    const int lane = tid & 63;

    __shared__ unsigned int hist[4096];
    __shared__ unsigned int cand[CAP];
    __shared__ unsigned int wtot[NWAVES], wsuf[NWAVES];
    __shared__ double dred[NWAVES];
    __shared__ float s_mean, s_alpha, s_beta;
    __shared__ unsigned int s_bin, s_cnt, s_ccnt, s_nB;

    if (tid == 0) { s_ccnt = 0u; s_nB = 0u; }
    __syncthreads();

    // idx(g) = ((g>>8)*256 + c)*256 + (g&255); thread g = tid, +1024 per i
    const size_t base = ((size_t)(tid >> 8) << 16) + ((size_t)c << 8) + (size_t)(tid & 255);
    const float4* xp = x4 + base;

    // ---- Pass 1: mean sum + candidate collection (|x| >= T_FAST) ----
    double s = 0.0;
    #pragma unroll
    for (int i = 0; i < 16; ++i) {
        float4 q = xp[(size_t)i * F4_STRIDE];
        s += ((double)q.x + (double)q.y) + ((double)q.z + (double)q.w);
        FOR4(q, v, {
            wave_append(fabsf(v) >= T_FAST, __float_as_uint(v),
                        cand, CAP, &s_ccnt, lane);
        })
    }
    double tot = block_sum_double(s, dred, tid);
    if (tid == 0) s_mean = (float)(tot / (double)M_DIM);
    __syncthreads();
    const float mean = s_mean;
    const unsigned int cntTotal = s_ccnt;
    const bool overflow = cntTotal > CAP;
    const unsigned int cnt = overflow ? CAP : cntTotal;

    // Non-collected values have |x-mean| < B; top-K provably collected iff
    // >= K collected values exceed B (exact check below).
    const float Babs = T_FAST + fabsf(mean);
    const unsigned int Bbits = __float_as_uint(Babs);

    bool fast_ok = false;
    if (!overflow) {
        const unsigned int iters = (cnt + THREADS - 1) / THREADS;
        for (unsigned int it = 0; it < iters; ++it) {
            const unsigned int i = it * THREADS + tid;
            bool pred = false;
            if (i < cnt) {
                float xv = __uint_as_float(cand[i]);
                unsigned int u = __float_as_uint(fabsf(xv - mean));
                cand[i] = u;
                pred = (u > Bbits);
            }
            unsigned long long m = __ballot(pred);
            if (lane == 0 && m) atomicAdd(&s_nB, (unsigned int)__popcll(m));
        }
        __syncthreads();
        fast_ok = (s_nB >= K_TOP);
    }

    unsigned int vk_bits, cnt_gt;
    double sum_gt;

    if (fast_ok) {
        // ---- select entirely among LDS candidates ----
        #pragma unroll
        for (int i = 0; i < 4; ++i) hist[tid + (i << 10)] = 0u;
        __syncthreads();
        for (unsigned int i = tid; i < cnt; i += THREADS)
            atomicAdd(&hist[cand[i] >> 20], 1u);
        __syncthreads();
        select_bin(hist, 4096, K_TOP, wtot, wsuf, &s_bin, &s_cnt, tid);
        const unsigned int b1 = s_bin;
        cnt_gt = s_cnt;
        const unsigned int K2 = K_TOP - s_cnt;

        #pragma unroll
        for (int i = 0; i < 4; ++i) hist[tid + (i << 10)] = 0u;
        __syncthreads();
        for (unsigned int i = tid; i < cnt; i += THREADS) {
            unsigned int u = cand[i];
            if ((u >> 20) == b1) atomicAdd(&hist[(u >> 8) & 0xFFFu], 1u);
        }
        __syncthreads();
        select_bin(hist, 4096, K2, wtot, wsuf, &s_bin, &s_cnt, tid);
        const unsigned int b2 = s_bin;
        const unsigned int K3 = K2 - s_cnt;
        const unsigned int pfx24 = (b1 << 12) | b2;
        cnt_gt += s_cnt;

        if (tid < 256) hist[tid] = 0u;
        __syncthreads();
        for (unsigned int i = tid; i < cnt; i += THREADS) {
            unsigned int u = cand[i];
            if ((u >> 8) == pfx24) atomicAdd(&hist[u & 0xFFu], 1u);
        }
        __syncthreads();
        select_bin(hist, 256, K3, wtot, wsuf, &s_bin, &s_cnt, tid);
        cnt_gt += s_cnt;
        vk_bits = (pfx24 << 8) | s_bin;

        double sg = 0.0;
        for (unsigned int i = tid; i < cnt; i += THREADS) {
            unsigned int u = cand[i];
            if (u > vk_bits) sg += (double)__uint_as_float(u);
        }
        sum_gt = block_sum_double(sg, dred, tid);
    } else {
        // ---- exact fallback: 4-pass global radix select (any input) ----
        #pragma unroll
        for (int i = 0; i < 4; ++i) hist[tid + (i << 10)] = 0u;
        __syncthreads();
        #pragma unroll
        for (int i = 0; i < 16; ++i) {
            float4 q = xp[(size_t)i * F4_STRIDE];
            FOR4(q, v, {
                unsigned int u = __float_as_uint(fabsf(v - mean));
                atomicAdd(&hist[u >> 20], 1u);
            })
        }
        __syncthreads();
        select_bin(hist, 4096, K_TOP, wtot, wsuf, &s_bin, &s_cnt, tid);
        const unsigned int b1 = s_bin;
        cnt_gt = s_cnt;
        const unsigned int K2 = K_TOP - s_cnt;

        #pragma unroll
        for (int i = 0; i < 4; ++i) hist[tid + (i << 10)] = 0u;
        __syncthreads();
        #pragma unroll
        for (int i = 0; i < 16; ++i) {
            float4 q = xp[(size_t)i * F4_STRIDE];
            FOR4(q, v, {
                unsigned int u = __float_as_uint(fabsf(v - mean));
                if ((u >> 20) == b1) atomicAdd(&hist[(u >> 8) & 0xFFFu], 1u);
            })
        }
        __syncthreads();
        select_bin(hist, 4096, K2, wtot, wsuf, &s_bin, &s_cnt, tid);
        const unsigned int b2 = s_bin;
        const unsigned int K3 = K2 - s_cnt;
        const unsigned int pfx24 = (b1 << 12) | b2;
        cnt_gt += s_cnt;

        if (tid < 256) hist[tid] = 0u;
        __syncthreads();
        #pragma unroll
        for (int i = 0; i < 16; ++i) {
            float4 q = xp[(size_t)i * F4_STRIDE];
            FOR4(q, v, {
                unsigned int u = __float_as_uint(fabsf(v - mean));
                if ((u >> 8) == pfx24) atomicAdd(&hist[u & 0xFFu], 1u);
            })
        }
        __syncthreads();
        select_bin(hist, 256, K3, wtot, wsuf, &s_bin, &s_cnt, tid);
        cnt_gt += s_cnt;
        vk_bits = (pfx24 << 8) | s_bin;

        double sg = 0.0;
        #pragma unroll
        for (int i = 0; i < 16; ++i) {
            float4 q = xp[(size_t)i * F4_STRIDE];
            FOR4(q, v, {
                float a = fabsf(v - mean);
                if (__float_as_uint(a) > vk_bits) sg += (double)a;
            })
        }
        sum_gt = block_sum_double(sg, dred, tid);
    }

    // ---- alpha/beta ----
    if (tid == 0) {
        const float vK = __uint_as_float(vk_bits);
        const double top_sum = sum_gt + (double)(K_TOP - cnt_gt) * (double)vK;
        const float mean_topk = (float)(top_sum / (double)K_TOP) * cconst;
        const float scale = 1.0f / (mean_topk + EPS_F);
        const float a = scale * weight[c];
        s_alpha = a;
        s_beta  = bias[c] - mean * a;
    }
    __syncthreads();

    // ---- Pass 2: apply (x L2/L3-hot), nontemporal stores ----
    const float a = s_alpha, b = s_beta;
    float4* op = out4 + base;
    #pragma unroll
    for (int i = 0; i < 16; ++i) {
        float4 q = xp[(size_t)i * F4_STRIDE];
        f4v o;
        o[0] = fmaf(q.x, a, b);
        o[1] = fmaf(q.y, a, b);
        o[2] = fmaf(q.z, a, b);
        o[3] = fmaf(q.w, a, b);
        __builtin_nontemporal_store(o, (f4v*)(op + (size_t)i * F4_STRIDE));
    }
}

// ---------------------------------------------------------------------------
extern "C" void kernel_launch(void* const* d_in, const int* in_sizes, int n_in,
                              void* d_out, int out_size, void* d_ws, size_t ws_size,
                              hipStream_t stream)
{
    const float* x = (const float*)d_in[0];
    const float* w = (const float*)d_in[1];
    const float* b = (const float*)d_in[2];
    float* out = (float*)d_out;

    const int M = in_sizes[0] / in_sizes[1];   // 65536
    const double cst = 0.5 * (1.0 + sqrt(M_PI * log(4.0))) / sqrt(2.0 * log((double)M));

    fused_kernel<<<C_DIM, THREADS, 0, stream>>>(
        (const float4*)x, w, b, (float4*)out, (float)cst);
}